// Round 1
// baseline (1196.766 us; speedup 1.0000x reference)
//
#include <hip/hip_runtime.h>
#include <hip/hip_bf16.h>
#include <math.h>

#define BATCH   2
#define SEQLEN  2048
#define DMODEL  1024
#define DINNER  2048
#define DSTATE  16
#define NHEADS  8
#define HEADDIM 256
#define DXBC    2080
#define NPACK   6184   // used cols of in_proj: 0..4095 (z0,x0) + 6144..8231 (xBC,dt)
#define NPAD    6272   // NPACK padded to 128
#define MROWS   4096   // BATCH*SEQLEN

typedef unsigned int u32;
typedef unsigned short u16;
typedef __attribute__((ext_vector_type(8))) short short8;
typedef __attribute__((ext_vector_type(4))) float f32x4;

#define GLOAD16(g, l) __builtin_amdgcn_global_load_lds( \
    (const __attribute__((address_space(1))) u32*)(g),  \
    (__attribute__((address_space(3))) u32*)(l), 16, 0, 0)

__device__ __forceinline__ u16 f2bf(float f) {
  union { float f; u32 u; } v; v.f = f;
  u32 r = v.u + 0x7fff + ((v.u >> 16) & 1);
  return (u16)(r >> 16);
}
__device__ __forceinline__ float bf2f(u16 b) {
  union { u32 u; float f; } v; v.u = ((u32)b) << 16;
  return v.f;
}

// ---------------- conversion kernels ----------------
__global__ void cvt_bf16(const float* __restrict__ s, u16* __restrict__ d, int n4) {
  int i = blockIdx.x * 256 + threadIdx.x;
  if (i >= n4) return;
  float4 v = ((const float4*)s)[i];
  ushort4 o = make_ushort4(f2bf(v.x), f2bf(v.y), f2bf(v.z), f2bf(v.w));
  ((ushort4*)d)[i] = o;
}

__global__ void cvt_pack_win(const float* __restrict__ W, u16* __restrict__ Wp) {
  int i = blockIdx.x * 256 + threadIdx.x;          // over NPAD*256 float4s
  if (i >= NPAD * 256) return;
  int row = i >> 8, c4 = i & 255;
  ushort4 o = make_ushort4(0, 0, 0, 0);
  if (row < NPACK) {
    int orig = row < 4096 ? row : row + 2048;      // skip unused 2048 cols
    float4 v = ((const float4*)(W + (size_t)orig * DMODEL))[c4];
    o = make_ushort4(f2bf(v.x), f2bf(v.y), f2bf(v.z), f2bf(v.w));
  }
  ((ushort4*)Wp)[i] = o;
}

// ---------------- GEMM (NT, bf16 in / fp32 acc) ----------------
// A: MxK row-major bf16, B: NxK row-major bf16 (i.e. B^T input), C[m,n]=sum_k A[m,k]B[n,k]
// 128x128 tile, BK=32, 4 waves (2x2), each wave 64x64 = 4x4 frags of 16x16x32 MFMA.
// EPI 0: store bf16 at outp[row*ldo+col]
// EPI 1: gate: g=sigmoid(acc+bias[col]); store bf16 g*gate_in[row*2048+col] at outp[row*4096+2048+col]
// EPI 2: store fp32 at outp[row*ldo+col]
template <int EPI>
__global__ __launch_bounds__(256, 2) void gemm_nt(
    const u16* __restrict__ A, const u16* __restrict__ B, int K, int ldo,
    void* __restrict__ outp, const float* __restrict__ bias,
    const u16* __restrict__ gate_in) {
  __shared__ u16 As[128][32];
  __shared__ u16 Bs[128][32];
  const int tid = threadIdx.x;
  const int wid = tid >> 6, lane = tid & 63;
  const int wm = wid >> 1, wn = wid & 1;
  const int bm = blockIdx.x, bn = blockIdx.y;
  const size_t baseA = (size_t)bm * 128 * K;
  const size_t baseB = (size_t)bn * 128 * K;
  const int rA = lane >> 2;          // 0..15 (row within 16-row group)
  const int kA = (lane & 3) * 8;     // element offset in k

  f32x4 acc[4][4];
  #pragma unroll
  for (int m = 0; m < 4; ++m)
    #pragma unroll
    for (int n = 0; n < 4; ++n) acc[m][n] = (f32x4){0.f, 0.f, 0.f, 0.f};

  for (int k0 = 0; k0 < K; k0 += 32) {
    __syncthreads();
    {
      const u16* gA0 = A + baseA + (size_t)(32 * wid + rA) * K + k0 + kA;
      const u16* gA1 = gA0 + (size_t)16 * K;
      GLOAD16(gA0, (char*)&As[0][0] + wid * 2048);
      GLOAD16(gA1, (char*)&As[0][0] + wid * 2048 + 1024);
      const u16* gB0 = B + baseB + (size_t)(32 * wid + rA) * K + k0 + kA;
      const u16* gB1 = gB0 + (size_t)16 * K;
      GLOAD16(gB0, (char*)&Bs[0][0] + wid * 2048);
      GLOAD16(gB1, (char*)&Bs[0][0] + wid * 2048 + 1024);
    }
    __syncthreads();
    const int fr = lane & 15, fk = (lane >> 4) * 8;
    short8 af[4], bfg[4];
    #pragma unroll
    for (int m = 0; m < 4; ++m) af[m] = *(const short8*)&As[wm * 64 + m * 16 + fr][fk];
    #pragma unroll
    for (int n = 0; n < 4; ++n) bfg[n] = *(const short8*)&Bs[wn * 64 + n * 16 + fr][fk];
    #pragma unroll
    for (int m = 0; m < 4; ++m)
      #pragma unroll
      for (int n = 0; n < 4; ++n)
        acc[m][n] = __builtin_amdgcn_mfma_f32_16x16x32_bf16(af[m], bfg[n], acc[m][n], 0, 0, 0);
  }

  const int er = (lane >> 4) * 4, ec = lane & 15;
  #pragma unroll
  for (int m = 0; m < 4; ++m) {
    #pragma unroll
    for (int n = 0; n < 4; ++n) {
      #pragma unroll
      for (int j = 0; j < 4; ++j) {
        int row = bm * 128 + wm * 64 + m * 16 + er + j;
        int col = bn * 128 + wn * 64 + n * 16 + ec;
        float v = acc[m][n][j];
        if (EPI == 0) {
          ((u16*)outp)[(size_t)row * ldo + col] = f2bf(v);
        } else if (EPI == 1) {
          float g = 1.f / (1.f + __expf(-(v + bias[col])));
          float nv = bf2f(gate_in[(size_t)row * 2048 + col]);
          ((u16*)outp)[(size_t)row * 4096 + 2048 + col] = f2bf(g * nv);
        } else {
          ((float*)outp)[(size_t)row * ldo + col] = v;
        }
      }
    }
  }
}

// ---------------- conv1d (depthwise, causal 4) + SiLU + split ----------------
__global__ void conv_silu(const u16* __restrict__ zx, const float* __restrict__ cw,
                          const float* __restrict__ cb, u16* __restrict__ xc,
                          float* __restrict__ bc) {
  int idx = blockIdx.x * 256 + threadIdx.x;
  if (idx >= MROWS * DXBC) return;
  int c = idx % DXBC;
  int m = idx / DXBC;
  int l = m & (SEQLEN - 1);
  float acc = cb[c];
  float w0 = cw[c * 4 + 0], w1 = cw[c * 4 + 1], w2 = cw[c * 4 + 2], w3 = cw[c * 4 + 3];
  const u16* col = zx + (size_t)m * NPAD + 4096 + c;
  acc += w3 * bf2f(col[0]);
  if (l >= 1) acc += w2 * bf2f(col[-NPAD]);
  if (l >= 2) acc += w1 * bf2f(col[-2 * NPAD]);
  if (l >= 3) acc += w0 * bf2f(col[-3 * NPAD]);
  float sv = acc / (1.f + __expf(-acc));   // silu
  if (c < DINNER) xc[(size_t)m * DINNER + c] = f2bf(sv);
  else bc[(size_t)m * 32 + (c - DINNER)] = sv;
}

// ---------------- dt = softplus(raw + bias); dA = exp(dt*A) ----------------
__global__ void dt_kernel(const u16* __restrict__ zx, const float* __restrict__ dt_bias,
                          const float* __restrict__ A_log, float* __restrict__ dtb,
                          float* __restrict__ dAb) {
  int idx = blockIdx.x * 256 + threadIdx.x;   // MROWS*NHEADS
  if (idx >= MROWS * NHEADS) return;
  int hd = idx & 7, m = idx >> 3;
  float raw = bf2f(zx[(size_t)m * NPAD + 6176 + hd]) + dt_bias[hd];
  float dtv = raw > 20.f ? raw : log1pf(expf(raw));
  float Av = -expf(A_log[hd]);
  dtb[idx] = dtv;
  dAb[idx] = expf(dtv * Av);
}

// ---------------- mlp_skip = silu(z0)*x0 -> hcat[:, :2048] ----------------
__global__ void mlp_skip(const u16* __restrict__ zx, u16* __restrict__ hcat) {
  int i = blockIdx.x * 256 + threadIdx.x;    // MROWS*512
  int m = i >> 9, c4 = (i & 511) * 4;
  const u16* row = zx + (size_t)m * NPAD;
  ushort4 zv = *(const ushort4*)(row + c4);
  ushort4 xv = *(const ushort4*)(row + 2048 + c4);
  float z0, x0;
  ushort4 o;
  z0 = bf2f(zv.x); x0 = bf2f(xv.x); o.x = f2bf(x0 * z0 / (1.f + __expf(-z0)));
  z0 = bf2f(zv.y); x0 = bf2f(xv.y); o.y = f2bf(x0 * z0 / (1.f + __expf(-z0)));
  z0 = bf2f(zv.z); x0 = bf2f(xv.z); o.z = f2bf(x0 * z0 / (1.f + __expf(-z0)));
  z0 = bf2f(zv.w); x0 = bf2f(xv.w); o.w = f2bf(x0 * z0 / (1.f + __expf(-z0)));
  *(ushort4*)(hcat + (size_t)m * 4096 + c4) = o;
}

// ---------------- selective scan: one block per (b,h), thread = p ----------------
__global__ __launch_bounds__(256) void scan_kernel(
    const u16* __restrict__ xc, const float* __restrict__ bc,
    const float* __restrict__ dtb, const float* __restrict__ dAb,
    const float* __restrict__ D_par, float* __restrict__ y) {
  const int b = blockIdx.x >> 3, hd = blockIdx.x & 7;
  const int p = threadIdx.x;
  const float Dv = D_par[hd];
  float h[16];
  #pragma unroll
  for (int n = 0; n < 16; ++n) h[n] = 0.f;
  __shared__ float sB[128][16], sC[128][16], sdt[128], sdA[128];
  const size_t rowbase = (size_t)b * SEQLEN;

  for (int t0 = 0; t0 < SEQLEN; t0 += 128) {
    __syncthreads();
    for (int i = threadIdx.x; i < 128 * 32; i += 256) {
      int tt = i >> 5, n = i & 31;
      float v = bc[(rowbase + t0 + tt) * 32 + n];
      if (n < 16) sB[tt][n] = v; else sC[tt][n - 16] = v;
    }
    if (threadIdx.x < 128) sdt[threadIdx.x] = dtb[(rowbase + t0 + threadIdx.x) * 8 + hd];
    else sdA[threadIdx.x - 128] = dAb[(rowbase + t0 + threadIdx.x - 128) * 8 + hd];
    __syncthreads();
    for (int ti = 0; ti < 128; ++ti) {
      const size_t t = rowbase + t0 + ti;
      float xv = bf2f(xc[t * DINNER + hd * HEADDIM + p]);
      float dtv = sdt[ti], dAv = sdA[ti];
      float dtx = dtv * xv;
      float yv = Dv * xv;
      const float4* Bq = (const float4*)sB[ti];
      const float4* Cq = (const float4*)sC[ti];
      #pragma unroll
      for (int q = 0; q < 4; ++q) {
        float4 Bv = Bq[q], Cv = Cq[q];
        h[4 * q + 0] = dAv * h[4 * q + 0] + dtx * Bv.x; yv += h[4 * q + 0] * Cv.x;
        h[4 * q + 1] = dAv * h[4 * q + 1] + dtx * Bv.y; yv += h[4 * q + 1] * Cv.y;
        h[4 * q + 2] = dAv * h[4 * q + 2] + dtx * Bv.z; yv += h[4 * q + 2] * Cv.z;
        h[4 * q + 3] = dAv * h[4 * q + 3] + dtx * Bv.w; yv += h[4 * q + 3] * Cv.w;
      }
      y[t * DINNER + hd * HEADDIM + p] = yv;
    }
  }
}

// ---------------- layernorm -> bf16 ----------------
__global__ __launch_bounds__(256) void ln_kernel(const float* __restrict__ y,
                                                 const float* __restrict__ gamma,
                                                 const float* __restrict__ beta,
                                                 u16* __restrict__ nrm) {
  const int row = blockIdx.x;
  const int t = threadIdx.x;
  const float* yr = y + (size_t)row * DINNER;
  float4 v0 = ((const float4*)yr)[t];
  float4 v1 = ((const float4*)yr)[256 + t];
  float s  = v0.x + v0.y + v0.z + v0.w + v1.x + v1.y + v1.z + v1.w;
  float ss = v0.x * v0.x + v0.y * v0.y + v0.z * v0.z + v0.w * v0.w +
             v1.x * v1.x + v1.y * v1.y + v1.z * v1.z + v1.w * v1.w;
  #pragma unroll
  for (int o = 1; o < 64; o <<= 1) { s += __shfl_xor(s, o); ss += __shfl_xor(ss, o); }
  __shared__ float rs[4], rss[4];
  const int wid = t >> 6;
  if ((t & 63) == 0) { rs[wid] = s; rss[wid] = ss; }
  __syncthreads();
  s = rs[0] + rs[1] + rs[2] + rs[3];
  ss = rss[0] + rss[1] + rss[2] + rss[3];
  float mu = s * (1.f / DINNER);
  float var = ss * (1.f / DINNER) - mu * mu;
  float inv = rsqrtf(var + 1e-5f);
  float4 g0 = ((const float4*)gamma)[t], b0 = ((const float4*)beta)[t];
  float4 g1 = ((const float4*)gamma)[256 + t], b1 = ((const float4*)beta)[256 + t];
  ushort4 o0, o1;
  o0.x = f2bf((v0.x - mu) * inv * g0.x + b0.x);
  o0.y = f2bf((v0.y - mu) * inv * g0.y + b0.y);
  o0.z = f2bf((v0.z - mu) * inv * g0.z + b0.z);
  o0.w = f2bf((v0.w - mu) * inv * g0.w + b0.w);
  o1.x = f2bf((v1.x - mu) * inv * g1.x + b1.x);
  o1.y = f2bf((v1.y - mu) * inv * g1.y + b1.y);
  o1.z = f2bf((v1.z - mu) * inv * g1.z + b1.z);
  o1.w = f2bf((v1.w - mu) * inv * g1.w + b1.w);
  ((ushort4*)(nrm + (size_t)row * DINNER))[t] = o0;
  ((ushort4*)(nrm + (size_t)row * DINNER))[256 + t] = o1;
}

// ---------------- host ----------------
extern "C" void kernel_launch(void* const* d_in, const int* in_sizes, int n_in,
                              void* d_out, int out_size, void* d_ws, size_t ws_size,
                              hipStream_t stream) {
  (void)in_sizes; (void)n_in; (void)out_size; (void)ws_size;
  const float* u       = (const float*)d_in[0];
  const float* W_in    = (const float*)d_in[1];
  const float* conv_w  = (const float*)d_in[2];
  const float* conv_b  = (const float*)d_in[3];
  const float* dt_bias = (const float*)d_in[4];
  const float* A_log   = (const float*)d_in[5];
  const float* D_par   = (const float*)d_in[6];
  const float* ln_g    = (const float*)d_in[7];
  const float* ln_b    = (const float*)d_in[8];
  const float* W_gate  = (const float*)d_in[9];
  const float* b_gate  = (const float*)d_in[10];
  const float* W_out   = (const float*)d_in[11];
  float* out = (float*)d_out;

  size_t off = 0;
  auto take = [&](size_t bytes) -> char* {
    char* p = (char*)d_ws + off;
    off = (off + bytes + 255) & ~(size_t)255;
    return p;
  };
  u16* u16b  = (u16*)take((size_t)MROWS * DMODEL * 2);
  u16* Wp    = (u16*)take((size_t)NPAD * DMODEL * 2);
  u16* Wg    = (u16*)take((size_t)DINNER * DINNER * 2);
  u16* Wo    = (u16*)take((size_t)DMODEL * 2 * DINNER * 2);
  u16* zx    = (u16*)take((size_t)MROWS * NPAD * 2);
  u16* xc    = (u16*)take((size_t)MROWS * DINNER * 2);
  float* bcb = (float*)take((size_t)MROWS * 32 * 4);
  float* dtb = (float*)take((size_t)MROWS * NHEADS * 4);
  float* dAb = (float*)take((size_t)MROWS * NHEADS * 4);
  u16* nrm   = (u16*)take((size_t)MROWS * DINNER * 2);
  u16* hcat  = (u16*)take((size_t)MROWS * 2 * DINNER * 2);
  float* y   = (float*)zx;   // alias: zx dead after conv/dt/mlp_skip

  cvt_bf16<<<MROWS * DMODEL / 4 / 256, 256, 0, stream>>>(u, u16b, MROWS * DMODEL / 4);
  cvt_pack_win<<<NPAD, 256, 0, stream>>>(W_in, Wp);
  cvt_bf16<<<DINNER * DINNER / 4 / 256, 256, 0, stream>>>(W_gate, Wg, DINNER * DINNER / 4);
  cvt_bf16<<<DMODEL * 2 * DINNER / 4 / 256, 256, 0, stream>>>(W_out, Wo, DMODEL * 2 * DINNER / 4);

  gemm_nt<0><<<dim3(MROWS / 128, NPAD / 128), 256, 0, stream>>>(
      u16b, Wp, DMODEL, NPAD, zx, nullptr, nullptr);

  conv_silu<<<(MROWS * DXBC + 255) / 256, 256, 0, stream>>>(zx, conv_w, conv_b, xc, bcb);
  dt_kernel<<<MROWS * NHEADS / 256, 256, 0, stream>>>(zx, dt_bias, A_log, dtb, dAb);
  mlp_skip<<<MROWS * 512 / 256, 256, 0, stream>>>(zx, hcat);

  scan_kernel<<<BATCH * NHEADS, 256, 0, stream>>>(xc, bcb, dtb, dAb, D_par, y);

  ln_kernel<<<MROWS, 256, 0, stream>>>(y, ln_g, ln_b, nrm);

  gemm_nt<1><<<dim3(MROWS / 128, DINNER / 128), 256, 0, stream>>>(
      nrm, Wg, DINNER, DINNER, hcat, b_gate, nrm);

  gemm_nt<2><<<dim3(MROWS / 128, DMODEL / 128), 256, 0, stream>>>(
      hcat, Wo, 2 * DINNER, DMODEL, out, nullptr, nullptr);
}

// Round 2
// 306.153 us; speedup vs baseline: 3.9090x; 3.9090x over previous
//
#include <hip/hip_runtime.h>
#include <hip/hip_bf16.h>
#include <math.h>

#define BATCH   2
#define SEQLEN  2048
#define DMODEL  1024
#define DINNER  2048
#define DSTATE  16
#define NHEADS  8
#define HEADDIM 256
#define DXBC    2080
#define NPACK   6184   // used cols of in_proj: 0..4095 (z0,x0) + 6144..8231 (xBC,dt)
#define NPAD    6272   // NPACK padded to 128
#define MROWS   4096   // BATCH*SEQLEN
#define CHUNK   64
#define NCHUNK  32
#define BH      16

typedef unsigned int u32;
typedef unsigned short u16;
typedef __attribute__((ext_vector_type(8))) short short8;
typedef __attribute__((ext_vector_type(4))) float f32x4;

#define GLOAD16(g, l) __builtin_amdgcn_global_load_lds( \
    (const __attribute__((address_space(1))) u32*)(g),  \
    (__attribute__((address_space(3))) u32*)(l), 16, 0, 0)

__device__ __forceinline__ u16 f2bf(float f) {
  union { float f; u32 u; } v; v.f = f;
  u32 r = v.u + 0x7fff + ((v.u >> 16) & 1);
  return (u16)(r >> 16);
}
__device__ __forceinline__ float bf2f(u16 b) {
  union { u32 u; float f; } v; v.u = ((u32)b) << 16;
  return v.f;
}

// ---------------- conversion kernels ----------------
__global__ void cvt_bf16(const float* __restrict__ s, u16* __restrict__ d, int n4) {
  int i = blockIdx.x * 256 + threadIdx.x;
  if (i >= n4) return;
  float4 v = ((const float4*)s)[i];
  ushort4 o = make_ushort4(f2bf(v.x), f2bf(v.y), f2bf(v.z), f2bf(v.w));
  ((ushort4*)d)[i] = o;
}

__global__ void cvt_pack_win(const float* __restrict__ W, u16* __restrict__ Wp) {
  int i = blockIdx.x * 256 + threadIdx.x;          // over NPAD*256 float4s
  if (i >= NPAD * 256) return;
  int row = i >> 8, c4 = i & 255;
  ushort4 o = make_ushort4(0, 0, 0, 0);
  if (row < NPACK) {
    int orig = row < 4096 ? row : row + 2048;      // skip unused 2048 cols
    float4 v = ((const float4*)(W + (size_t)orig * DMODEL))[c4];
    o = make_ushort4(f2bf(v.x), f2bf(v.y), f2bf(v.z), f2bf(v.w));
  }
  ((ushort4*)Wp)[i] = o;
}

// ---------------- GEMM (NT, bf16 in / fp32 acc) ----------------
template <int EPI>
__global__ __launch_bounds__(256, 2) void gemm_nt(
    const u16* __restrict__ A, const u16* __restrict__ B, int K, int ldo,
    void* __restrict__ outp, const float* __restrict__ bias,
    const u16* __restrict__ gate_in) {
  __shared__ u16 As[128][32];
  __shared__ u16 Bs[128][32];
  const int tid = threadIdx.x;
  const int wid = tid >> 6, lane = tid & 63;
  const int wm = wid >> 1, wn = wid & 1;
  const int bm = blockIdx.x, bn = blockIdx.y;
  const size_t baseA = (size_t)bm * 128 * K;
  const size_t baseB = (size_t)bn * 128 * K;
  const int rA = lane >> 2;
  const int kA = (lane & 3) * 8;

  f32x4 acc[4][4];
  #pragma unroll
  for (int m = 0; m < 4; ++m)
    #pragma unroll
    for (int n = 0; n < 4; ++n) acc[m][n] = (f32x4){0.f, 0.f, 0.f, 0.f};

  for (int k0 = 0; k0 < K; k0 += 32) {
    __syncthreads();
    {
      const u16* gA0 = A + baseA + (size_t)(32 * wid + rA) * K + k0 + kA;
      const u16* gA1 = gA0 + (size_t)16 * K;
      GLOAD16(gA0, (char*)&As[0][0] + wid * 2048);
      GLOAD16(gA1, (char*)&As[0][0] + wid * 2048 + 1024);
      const u16* gB0 = B + baseB + (size_t)(32 * wid + rA) * K + k0 + kA;
      const u16* gB1 = gB0 + (size_t)16 * K;
      GLOAD16(gB0, (char*)&Bs[0][0] + wid * 2048);
      GLOAD16(gB1, (char*)&Bs[0][0] + wid * 2048 + 1024);
    }
    __syncthreads();
    const int fr = lane & 15, fk = (lane >> 4) * 8;
    short8 af[4], bfg[4];
    #pragma unroll
    for (int m = 0; m < 4; ++m) af[m] = *(const short8*)&As[wm * 64 + m * 16 + fr][fk];
    #pragma unroll
    for (int n = 0; n < 4; ++n) bfg[n] = *(const short8*)&Bs[wn * 64 + n * 16 + fr][fk];
    #pragma unroll
    for (int m = 0; m < 4; ++m)
      #pragma unroll
      for (int n = 0; n < 4; ++n)
        acc[m][n] = __builtin_amdgcn_mfma_f32_16x16x32_bf16(af[m], bfg[n], acc[m][n], 0, 0, 0);
  }

  const int er = (lane >> 4) * 4, ec = lane & 15;
  #pragma unroll
  for (int m = 0; m < 4; ++m) {
    #pragma unroll
    for (int n = 0; n < 4; ++n) {
      #pragma unroll
      for (int j = 0; j < 4; ++j) {
        int row = bm * 128 + wm * 64 + m * 16 + er + j;
        int col = bn * 128 + wn * 64 + n * 16 + ec;
        float v = acc[m][n][j];
        if (EPI == 0) {
          ((u16*)outp)[(size_t)row * ldo + col] = f2bf(v);
        } else if (EPI == 1) {
          float g = 1.f / (1.f + __expf(-(v + bias[col])));
          float nv = bf2f(gate_in[(size_t)row * 2048 + col]);
          ((u16*)outp)[(size_t)row * 4096 + 2048 + col] = f2bf(g * nv);
        } else {
          ((float*)outp)[(size_t)row * ldo + col] = v;
        }
      }
    }
  }
}

// ---------------- conv1d (depthwise, causal 4) + SiLU + split ----------------
__global__ void conv_silu(const u16* __restrict__ zx, const float* __restrict__ cw,
                          const float* __restrict__ cb, u16* __restrict__ xc,
                          float* __restrict__ bc) {
  int idx = blockIdx.x * 256 + threadIdx.x;
  if (idx >= MROWS * DXBC) return;
  int c = idx % DXBC;
  int m = idx / DXBC;
  int l = m & (SEQLEN - 1);
  float acc = cb[c];
  float w0 = cw[c * 4 + 0], w1 = cw[c * 4 + 1], w2 = cw[c * 4 + 2], w3 = cw[c * 4 + 3];
  const u16* col = zx + (size_t)m * NPAD + 4096 + c;
  acc += w3 * bf2f(col[0]);
  if (l >= 1) acc += w2 * bf2f(col[-NPAD]);
  if (l >= 2) acc += w1 * bf2f(col[-2 * NPAD]);
  if (l >= 3) acc += w0 * bf2f(col[-3 * NPAD]);
  float sv = acc / (1.f + __expf(-acc));   // silu
  if (c < DINNER) xc[(size_t)m * DINNER + c] = f2bf(sv);
  else bc[(size_t)m * 32 + (c - DINNER)] = sv;
}

// ---------------- dt = softplus(raw + bias) ----------------
__global__ void dt_kernel(const u16* __restrict__ zx, const float* __restrict__ dt_bias,
                          float* __restrict__ dtb) {
  int idx = blockIdx.x * 256 + threadIdx.x;   // MROWS*NHEADS
  if (idx >= MROWS * NHEADS) return;
  int hd = idx & 7, m = idx >> 3;
  float raw = bf2f(zx[(size_t)m * NPAD + 6176 + hd]) + dt_bias[hd];
  float dtv = raw > 20.f ? raw : log1pf(expf(raw));
  dtb[idx] = dtv;
}

// ---------------- mlp_skip = silu(z0)*x0 -> hcat[:, :2048] ----------------
__global__ void mlp_skip(const u16* __restrict__ zx, u16* __restrict__ hcat) {
  int i = blockIdx.x * 256 + threadIdx.x;    // MROWS*512
  int m = i >> 9, c4 = (i & 511) * 4;
  const u16* row = zx + (size_t)m * NPAD;
  ushort4 zv = *(const ushort4*)(row + c4);
  ushort4 xv = *(const ushort4*)(row + 2048 + c4);
  float z0, x0;
  ushort4 o;
  z0 = bf2f(zv.x); x0 = bf2f(xv.x); o.x = f2bf(x0 * z0 / (1.f + __expf(-z0)));
  z0 = bf2f(zv.y); x0 = bf2f(xv.y); o.y = f2bf(x0 * z0 / (1.f + __expf(-z0)));
  z0 = bf2f(zv.z); x0 = bf2f(xv.z); o.z = f2bf(x0 * z0 / (1.f + __expf(-z0)));
  z0 = bf2f(zv.w); x0 = bf2f(xv.w); o.w = f2bf(x0 * z0 / (1.f + __expf(-z0)));
  *(ushort4*)(hcat + (size_t)m * 4096 + c4) = o;
}

// ================= SSD chunked scan =================
// LDS x tile: 64 rows x 256 cols bf16, 16B-chunk XOR swizzle, 32KB, no pad.
__device__ __forceinline__ int xs_addr(int r, int p) {  // byte offset
  return r * 512 + ((((p >> 3) ^ ((r >> 3) & 3)) & 31) << 4) + (p & 7) * 2;
}
__device__ __forceinline__ int P_addr(int t, int s) {   // byte offset, 64x64 bf16
  return t * 128 + ((((s >> 3) ^ (t & 7)) & 7) << 4) + (s & 7) * 2;
}

__device__ __forceinline__ void stage_x(u16* xs, const u16* __restrict__ xc,
                                        size_t base, int tid) {
  #pragma unroll
  for (int it = 0; it < 8; ++it) {
    int r = it * 8 + (tid >> 5);
    int pc = (tid & 31) * 8;
    short8 v = *(const short8*)(xc + base + (size_t)r * DINNER + pc);
    *(short8*)((char*)xs + xs_addr(r, pc)) = v;
  }
}

__device__ __forceinline__ short8 xfrag(const u16* xs, int k0, int g, int p) {
  short8 v;
  #pragma unroll
  for (int j = 0; j < 8; ++j) {
    int s = k0 + g * 8 + j;
    v[j] = *(const short*)((const char*)xs + xs_addr(s, p));
  }
  return v;
}

// S1: per-(bh,chunk) state S_c[n][p] and log-decay prefix lc
__global__ __launch_bounds__(256) void ssd_state(
    const u16* __restrict__ xc, const float* __restrict__ bcb,
    const float* __restrict__ dtb, const float* __restrict__ A_log,
    float* __restrict__ Sbuf, float* __restrict__ lcbuf) {
  __shared__ u16 xs[64 * 256];
  __shared__ float sLC[64], sDT[64];
  __shared__ float wBT[16][65];
  const int tid = threadIdx.x;
  const int bh = blockIdx.x >> 5, c = blockIdx.x & 31;
  const int b = bh >> 3, h = bh & 7;
  const size_t row0 = (size_t)b * SEQLEN + c * CHUNK;
  stage_x(xs, xc, row0 * DINNER + h * HEADDIM, tid);
  if (tid < 64) {
    float dtv = dtb[(row0 + tid) * NHEADS + h];
    float A = -__expf(A_log[h]);
    float s = dtv * A;
    #pragma unroll
    for (int off = 1; off < 64; off <<= 1) {
      float v = __shfl_up(s, off, 64);
      if (tid >= off) s += v;
    }
    sLC[tid] = s; sDT[tid] = dtv;
    lcbuf[(size_t)blockIdx.x * 64 + tid] = s;
  }
  __syncthreads();
  const float lc63 = sLC[63];
  for (int i = tid; i < 1024; i += 256) {
    int n = i & 15, t = i >> 4;
    float w = sDT[t] * __expf(lc63 - sLC[t]);
    wBT[n][t] = w * bcb[(row0 + t) * 32 + n];
  }
  __syncthreads();
  const int lane = tid & 63, w = tid >> 6;
  const int cl = lane & 15, g = lane >> 4;
  f32x4 acc[4];
  #pragma unroll
  for (int pt = 0; pt < 4; ++pt) acc[pt] = (f32x4){0.f, 0.f, 0.f, 0.f};
  #pragma unroll
  for (int kk = 0; kk < 2; ++kk) {
    int k0 = kk * 32;
    short8 af;
    #pragma unroll
    for (int j = 0; j < 8; ++j) af[j] = (short)f2bf(wBT[cl][k0 + g * 8 + j]);
    #pragma unroll
    for (int pt = 0; pt < 4; ++pt) {
      short8 bf = xfrag(xs, k0, g, (w * 4 + pt) * 16 + cl);
      acc[pt] = __builtin_amdgcn_mfma_f32_16x16x32_bf16(af, bf, acc[pt], 0, 0, 0);
    }
  }
  float* Sc = Sbuf + (size_t)blockIdx.x * 16 * 256;
  #pragma unroll
  for (int pt = 0; pt < 4; ++pt)
    #pragma unroll
    for (int j = 0; j < 4; ++j)
      Sc[(g * 4 + j) * 256 + (w * 4 + pt) * 16 + cl] = acc[pt][j];
}

// S2: inter-chunk recurrence Sprev[c] = H_{c-1}
__global__ __launch_bounds__(256) void ssd_combine(
    const float* __restrict__ Sbuf, const float* __restrict__ lcbuf,
    float* __restrict__ Sprev) {
  const int bh = blockIdx.x >> 4, seg = blockIdx.x & 15;
  const int idx = seg * 256 + threadIdx.x;   // n*256+p
  float r = 0.f;
  #pragma unroll 1
  for (int c = 0; c < NCHUNK; ++c) {
    size_t o = ((size_t)bh * NCHUNK + c) * 4096 + idx;
    Sprev[o] = r;
    float lam = __expf(lcbuf[((size_t)bh * NCHUNK + c) * 64 + 63]);
    r = lam * r + Sbuf[o];
  }
}

// S3: intra-chunk (CB^T masked) @ X + Ce @ Sprev^T + D*x -> y (bf16)
__global__ __launch_bounds__(256) void ssd_out(
    const u16* __restrict__ xc, const float* __restrict__ bcb,
    const float* __restrict__ dtb, const float* __restrict__ lcbuf,
    const float* __restrict__ Sprev, const float* __restrict__ D_par,
    u16* __restrict__ y) {
  __shared__ u16 xs[64 * 256];
  __shared__ u16 P[64 * 64];
  __shared__ u16 sB[64][17], sC[64][17], sCe[64][17];
  __shared__ u16 sSp[256][17];
  __shared__ float sLC[64], sDT[64];
  const int tid = threadIdx.x;
  const int bh = blockIdx.x >> 5, c = blockIdx.x & 31;
  const int b = bh >> 3, h = bh & 7;
  const size_t row0 = (size_t)b * SEQLEN + c * CHUNK;
  stage_x(xs, xc, row0 * DINNER + h * HEADDIM, tid);
  if (tid < 64) {
    sLC[tid] = lcbuf[(size_t)blockIdx.x * 64 + tid];
    sDT[tid] = dtb[(row0 + tid) * NHEADS + h];
  }
  // B, C, Ce (Ce reads lcbuf from global, no LDS dependency)
  for (int i = tid; i < 1024; i += 256) {
    int n = i & 15, t = i >> 4;
    float Bv = bcb[(row0 + t) * 32 + n];
    float Cv = bcb[(row0 + t) * 32 + 16 + n];
    float e = __expf(lcbuf[(size_t)blockIdx.x * 64 + t]);
    sB[t][n] = f2bf(Bv);
    sC[t][n] = f2bf(Cv);
    sCe[t][n] = f2bf(Cv * e);
  }
  // Sprev -> LDS transposed (bf16)
  {
    const float* Sp = Sprev + (size_t)blockIdx.x * 4096;
    int p = tid & 255;
    if (tid < 256) {
      #pragma unroll
      for (int n = 0; n < 16; ++n) sSp[p][n] = f2bf(Sp[n * 256 + p]);
    }
  }
  __syncthreads();

  const int lane = tid & 63, w = tid >> 6;
  const int cl = lane & 15, g = lane >> 4;

  // ---- CB^T (K=16, zero-padded to 32) ----
  f32x4 gacc[4];
  #pragma unroll
  for (int st = 0; st < 4; ++st) gacc[st] = (f32x4){0.f, 0.f, 0.f, 0.f};
  short8 afc = (short8){0, 0, 0, 0, 0, 0, 0, 0};
  if (g < 2) {
    #pragma unroll
    for (int j = 0; j < 8; ++j) afc[j] = (short)sC[w * 16 + cl][g * 8 + j];
  }
  #pragma unroll
  for (int st = 0; st < 4; ++st) {
    short8 bfb = (short8){0, 0, 0, 0, 0, 0, 0, 0};
    if (g < 2) {
      #pragma unroll
      for (int j = 0; j < 8; ++j) bfb[j] = (short)sB[st * 16 + cl][g * 8 + j];
    }
    gacc[st] = __builtin_amdgcn_mfma_f32_16x16x32_bf16(afc, bfb, gacc[st], 0, 0, 0);
  }
  // ---- scale/mask -> P ----
  #pragma unroll
  for (int st = 0; st < 4; ++st) {
    #pragma unroll
    for (int j = 0; j < 4; ++j) {
      int t = w * 16 + g * 4 + j;
      int s = st * 16 + cl;
      float v = 0.f;
      if (s <= t) v = gacc[st][j] * sDT[s] * __expf(sLC[t] - sLC[s]);
      *(u16*)((char*)P + P_addr(t, s)) = f2bf(v);
    }
  }
  asm volatile("s_waitcnt lgkmcnt(0)" ::: "memory");
  __builtin_amdgcn_sched_barrier(0);

  // ---- Y = P@X (K=64) + Ce@Sp^T (K=16) ----
  f32x4 acc[16];
  #pragma unroll
  for (int pt = 0; pt < 16; ++pt) acc[pt] = (f32x4){0.f, 0.f, 0.f, 0.f};
  #pragma unroll
  for (int kk = 0; kk < 2; ++kk) {
    int k0 = kk * 32;
    short8 ap = *(const short8*)((const char*)P + P_addr(w * 16 + cl, k0 + g * 8));
    #pragma unroll
    for (int pt = 0; pt < 16; ++pt) {
      short8 bf = xfrag(xs, k0, g, pt * 16 + cl);
      acc[pt] = __builtin_amdgcn_mfma_f32_16x16x32_bf16(ap, bf, acc[pt], 0, 0, 0);
    }
  }
  {
    short8 ae = (short8){0, 0, 0, 0, 0, 0, 0, 0};
    if (g < 2) {
      #pragma unroll
      for (int j = 0; j < 8; ++j) ae[j] = (short)sCe[w * 16 + cl][g * 8 + j];
    }
    #pragma unroll
    for (int pt = 0; pt < 16; ++pt) {
      short8 bs = (short8){0, 0, 0, 0, 0, 0, 0, 0};
      if (g < 2) {
        #pragma unroll
        for (int j = 0; j < 8; ++j) bs[j] = (short)sSp[pt * 16 + cl][g * 8 + j];
      }
      acc[pt] = __builtin_amdgcn_mfma_f32_16x16x32_bf16(ae, bs, acc[pt], 0, 0, 0);
    }
  }
  // ---- epilogue: + D*x, write y bf16 ----
  const float Dv = D_par[h];
  #pragma unroll
  for (int pt = 0; pt < 16; ++pt) {
    #pragma unroll
    for (int j = 0; j < 4; ++j) {
      int t = w * 16 + g * 4 + j;
      int p = pt * 16 + cl;
      float xv = bf2f(*(const u16*)((const char*)xs + xs_addr(t, p)));
      float v = acc[pt][j] + Dv * xv;
      y[(row0 + t) * DINNER + h * HEADDIM + p] = f2bf(v);
    }
  }
}

// ---------------- layernorm (bf16 in) -> bf16 ----------------
__global__ __launch_bounds__(256) void ln_kernel(const u16* __restrict__ y,
                                                 const float* __restrict__ gamma,
                                                 const float* __restrict__ beta,
                                                 u16* __restrict__ nrm) {
  const int row = blockIdx.x;
  const int t = threadIdx.x;
  const u16* yr = y + (size_t)row * DINNER;
  short8 v = *(const short8*)(yr + t * 8);
  float f[8];
  float s = 0.f, ss = 0.f;
  #pragma unroll
  for (int j = 0; j < 8; ++j) {
    f[j] = bf2f((u16)v[j]);
    s += f[j]; ss += f[j] * f[j];
  }
  #pragma unroll
  for (int o = 1; o < 64; o <<= 1) { s += __shfl_xor(s, o); ss += __shfl_xor(ss, o); }
  __shared__ float rs[4], rss[4];
  const int wid = t >> 6;
  if ((t & 63) == 0) { rs[wid] = s; rss[wid] = ss; }
  __syncthreads();
  s = rs[0] + rs[1] + rs[2] + rs[3];
  ss = rss[0] + rss[1] + rss[2] + rss[3];
  float mu = s * (1.f / DINNER);
  float var = ss * (1.f / DINNER) - mu * mu;
  float inv = rsqrtf(var + 1e-5f);
  float4 g0 = ((const float4*)gamma)[t * 2], g1 = ((const float4*)gamma)[t * 2 + 1];
  float4 b0 = ((const float4*)beta)[t * 2], b1 = ((const float4*)beta)[t * 2 + 1];
  short8 o;
  o[0] = (short)f2bf((f[0] - mu) * inv * g0.x + b0.x);
  o[1] = (short)f2bf((f[1] - mu) * inv * g0.y + b0.y);
  o[2] = (short)f2bf((f[2] - mu) * inv * g0.z + b0.z);
  o[3] = (short)f2bf((f[3] - mu) * inv * g0.w + b0.w);
  o[4] = (short)f2bf((f[4] - mu) * inv * g1.x + b1.x);
  o[5] = (short)f2bf((f[5] - mu) * inv * g1.y + b1.y);
  o[6] = (short)f2bf((f[6] - mu) * inv * g1.z + b1.z);
  o[7] = (short)f2bf((f[7] - mu) * inv * g1.w + b1.w);
  *(short8*)(nrm + (size_t)row * DINNER + t * 8) = o;
}

// ---------------- host ----------------
extern "C" void kernel_launch(void* const* d_in, const int* in_sizes, int n_in,
                              void* d_out, int out_size, void* d_ws, size_t ws_size,
                              hipStream_t stream) {
  (void)in_sizes; (void)n_in; (void)out_size; (void)ws_size;
  const float* u       = (const float*)d_in[0];
  const float* W_in    = (const float*)d_in[1];
  const float* conv_w  = (const float*)d_in[2];
  const float* conv_b  = (const float*)d_in[3];
  const float* dt_bias = (const float*)d_in[4];
  const float* A_log   = (const float*)d_in[5];
  const float* D_par   = (const float*)d_in[6];
  const float* ln_g    = (const float*)d_in[7];
  const float* ln_b    = (const float*)d_in[8];
  const float* W_gate  = (const float*)d_in[9];
  const float* b_gate  = (const float*)d_in[10];
  const float* W_out   = (const float*)d_in[11];
  float* out = (float*)d_out;

  size_t off = 0;
  auto take = [&](size_t bytes) -> char* {
    char* p = (char*)d_ws + off;
    off = (off + bytes + 255) & ~(size_t)255;
    return p;
  };
  u16* u16b  = (u16*)take((size_t)MROWS * DMODEL * 2);          // 8MB, dead after gemm1
  u16* Wp    = (u16*)take((size_t)NPAD * DMODEL * 2);
  u16* Wg    = (u16*)take((size_t)DINNER * DINNER * 2);
  u16* Wo    = (u16*)take((size_t)DMODEL * 2 * DINNER * 2);
  u16* zx    = (u16*)take((size_t)MROWS * NPAD * 2);            // 51MB, dead after conv/dt/mlp
  u16* xc    = (u16*)take((size_t)MROWS * DINNER * 2);
  float* bcb = (float*)take((size_t)MROWS * 32 * 4);
  float* dtb = (float*)take((size_t)MROWS * NHEADS * 4);
  float* lcbuf = (float*)take((size_t)BH * NCHUNK * 64 * 4);
  u16* nrm   = (u16*)take((size_t)MROWS * DINNER * 2);
  u16* hcat  = (u16*)take((size_t)MROWS * 2 * DINNER * 2);
  float* Sbuf  = (float*)u16b;                // 8MB alias (u16b dead)
  u16*   y     = zx;                          // bf16 [4096][2048] = 16MB
  float* Sprev = (float*)((char*)zx + (size_t)16 * 1024 * 1024); // 8MB alias

  cvt_bf16<<<MROWS * DMODEL / 4 / 256, 256, 0, stream>>>(u, u16b, MROWS * DMODEL / 4);
  cvt_pack_win<<<NPAD, 256, 0, stream>>>(W_in, Wp);
  cvt_bf16<<<DINNER * DINNER / 4 / 256, 256, 0, stream>>>(W_gate, Wg, DINNER * DINNER / 4);
  cvt_bf16<<<DMODEL * 2 * DINNER / 4 / 256, 256, 0, stream>>>(W_out, Wo, DMODEL * 2 * DINNER / 4);

  gemm_nt<0><<<dim3(MROWS / 128, NPAD / 128), 256, 0, stream>>>(
      u16b, Wp, DMODEL, NPAD, zx, nullptr, nullptr);

  conv_silu<<<(MROWS * DXBC + 255) / 256, 256, 0, stream>>>(zx, conv_w, conv_b, xc, bcb);
  dt_kernel<<<MROWS * NHEADS / 256, 256, 0, stream>>>(zx, dt_bias, dtb);
  mlp_skip<<<MROWS * 512 / 256, 256, 0, stream>>>(zx, hcat);

  ssd_state<<<BH * NCHUNK, 256, 0, stream>>>(xc, bcb, dtb, A_log, Sbuf, lcbuf);
  ssd_combine<<<BH * 16, 256, 0, stream>>>(Sbuf, lcbuf, Sprev);
  ssd_out<<<BH * NCHUNK, 256, 0, stream>>>(xc, bcb, dtb, lcbuf, Sprev, D_par, y);

  ln_kernel<<<MROWS, 256, 0, stream>>>(y, ln_g, ln_b, nrm);

  gemm_nt<1><<<dim3(MROWS / 128, DINNER / 128), 256, 0, stream>>>(
      nrm, Wg, DINNER, DINNER, hcat, b_gate, nrm);

  gemm_nt<2><<<dim3(MROWS / 128, DMODEL / 128), 256, 0, stream>>>(
      hcat, Wo, 2 * DINNER, DMODEL, out, nullptr, nullptr);
}

// Round 3
// 277.335 us; speedup vs baseline: 4.3152x; 1.1039x over previous
//
#include <hip/hip_runtime.h>
#include <hip/hip_bf16.h>
#include <math.h>

#define BATCH   2
#define SEQLEN  2048
#define DMODEL  1024
#define DINNER  2048
#define DSTATE  16
#define NHEADS  8
#define HEADDIM 256
#define DXBC    2080
#define NPACK   6184   // used cols of in_proj: 0..4095 (z0,x0) + 6144..8231 (xBC,dt)
#define NPAD    6272   // NPACK padded to 128
#define MROWS   4096   // BATCH*SEQLEN
#define CHUNK   64
#define NCHUNK  32
#define BH      16

typedef unsigned int u32;
typedef unsigned short u16;
typedef __attribute__((ext_vector_type(8))) short short8;
typedef __attribute__((ext_vector_type(4))) float f32x4;

#define GLOAD16(g, l) __builtin_amdgcn_global_load_lds( \
    (const __attribute__((address_space(1))) u32*)(g),  \
    (__attribute__((address_space(3))) u32*)(l), 16, 0, 0)

__device__ __forceinline__ u16 f2bf(float f) {
  union { float f; u32 u; } v; v.f = f;
  u32 r = v.u + 0x7fff + ((v.u >> 16) & 1);
  return (u16)(r >> 16);
}
__device__ __forceinline__ float bf2f(u16 b) {
  union { u32 u; float f; } v; v.u = ((u32)b) << 16;
  return v.f;
}

struct Parts { float* p0; float* p1; float* p2; float* p3; };

// ---------------- fused conversions: u, W_gate, W_out (plain) + W_in (packed) ----------------
#define S_U   1048576           // MROWS*DMODEL/4
#define S_WG  1048576           // DINNER*DINNER/4
#define S_WO  1048576           // DMODEL*2*DINNER/4
#define S_WP  1605632           // NPAD*256
#define S_TOT (S_U + S_WG + S_WO + S_WP)

__global__ void cvt_all(const float* __restrict__ u, const float* __restrict__ Wg,
                        const float* __restrict__ Wo, const float* __restrict__ Win,
                        u16* __restrict__ ub, u16* __restrict__ Wgb,
                        u16* __restrict__ Wob, u16* __restrict__ Wp) {
  for (int i = blockIdx.x * 256 + threadIdx.x; i < S_TOT; i += gridDim.x * 256) {
    const float* src; u16* dst; int idx;
    if (i < S_U) { src = u; dst = ub; idx = i; }
    else if (i < S_U + S_WG) { src = Wg; dst = Wgb; idx = i - S_U; }
    else if (i < S_U + S_WG + S_WO) { src = Wo; dst = Wob; idx = i - S_U - S_WG; }
    else {
      int j = i - S_U - S_WG - S_WO;
      int row = j >> 8, c4 = j & 255;
      ushort4 o = make_ushort4(0, 0, 0, 0);
      if (row < NPACK) {
        int orig = row < 4096 ? row : row + 2048;
        float4 v = ((const float4*)(Win + (size_t)orig * DMODEL))[c4];
        o = make_ushort4(f2bf(v.x), f2bf(v.y), f2bf(v.z), f2bf(v.w));
      }
      ((ushort4*)Wp)[j] = o;
      continue;
    }
    float4 v = ((const float4*)src)[idx];
    ((ushort4*)dst)[idx] = make_ushort4(f2bf(v.x), f2bf(v.y), f2bf(v.z), f2bf(v.w));
  }
}

// ---------------- GEMM (NT, bf16 in / fp32 acc) ----------------
// A: M x ldk row-major bf16, B: N x ldk row-major bf16. C[m,n]=sum over K_loop at
// slice offset blockIdx.z*K_loop. 128x128 tile, BK=32, 4 waves.
// EPI 0: bf16 store at outp[row*ldo+col]
// EPI 1: gate epilogue -> hcat[row*4096+2048+col]
// EPI 3: fp32 partial store to parts.p[blockIdx.z][row*ldo+col]
template <int EPI>
__global__ __launch_bounds__(256, 2) void gemm_nt(
    const u16* __restrict__ A, const u16* __restrict__ B, int K_loop, int ldk, int ldo,
    void* __restrict__ outp, const float* __restrict__ bias,
    const u16* __restrict__ gate_in, Parts parts) {
  __shared__ u16 As[128][32];
  __shared__ u16 Bs[128][32];
  const int tid = threadIdx.x;
  const int wid = tid >> 6, lane = tid & 63;
  const int wm = wid >> 1, wn = wid & 1;
  const int bm = blockIdx.x, bn = blockIdx.y;
  const size_t baseA = (size_t)bm * 128 * ldk + (size_t)blockIdx.z * K_loop;
  const size_t baseB = (size_t)bn * 128 * ldk + (size_t)blockIdx.z * K_loop;
  const int rA = lane >> 2;
  const int kA = (lane & 3) * 8;

  f32x4 acc[4][4];
  #pragma unroll
  for (int m = 0; m < 4; ++m)
    #pragma unroll
    for (int n = 0; n < 4; ++n) acc[m][n] = (f32x4){0.f, 0.f, 0.f, 0.f};

  for (int k0 = 0; k0 < K_loop; k0 += 32) {
    __syncthreads();
    {
      const u16* gA0 = A + baseA + (size_t)(32 * wid + rA) * ldk + k0 + kA;
      const u16* gA1 = gA0 + (size_t)16 * ldk;
      GLOAD16(gA0, (char*)&As[0][0] + wid * 2048);
      GLOAD16(gA1, (char*)&As[0][0] + wid * 2048 + 1024);
      const u16* gB0 = B + baseB + (size_t)(32 * wid + rA) * ldk + k0 + kA;
      const u16* gB1 = gB0 + (size_t)16 * ldk;
      GLOAD16(gB0, (char*)&Bs[0][0] + wid * 2048);
      GLOAD16(gB1, (char*)&Bs[0][0] + wid * 2048 + 1024);
    }
    __syncthreads();
    const int fr = lane & 15, fk = (lane >> 4) * 8;
    short8 af[4], bfg[4];
    #pragma unroll
    for (int m = 0; m < 4; ++m) af[m] = *(const short8*)&As[wm * 64 + m * 16 + fr][fk];
    #pragma unroll
    for (int n = 0; n < 4; ++n) bfg[n] = *(const short8*)&Bs[wn * 64 + n * 16 + fr][fk];
    #pragma unroll
    for (int m = 0; m < 4; ++m)
      #pragma unroll
      for (int n = 0; n < 4; ++n)
        acc[m][n] = __builtin_amdgcn_mfma_f32_16x16x32_bf16(af[m], bfg[n], acc[m][n], 0, 0, 0);
  }

  const int er = (lane >> 4) * 4, ec = lane & 15;
  float* pp = nullptr;
  if (EPI == 3) {
    pp = blockIdx.z == 0 ? parts.p0 : blockIdx.z == 1 ? parts.p1
       : blockIdx.z == 2 ? parts.p2 : parts.p3;
  }
  #pragma unroll
  for (int m = 0; m < 4; ++m) {
    #pragma unroll
    for (int n = 0; n < 4; ++n) {
      #pragma unroll
      for (int j = 0; j < 4; ++j) {
        int row = bm * 128 + wm * 64 + m * 16 + er + j;
        int col = bn * 128 + wn * 64 + n * 16 + ec;
        float v = acc[m][n][j];
        if (EPI == 0) {
          ((u16*)outp)[(size_t)row * ldo + col] = f2bf(v);
        } else if (EPI == 1) {
          float g = 1.f / (1.f + __expf(-(v + bias[col])));
          float nv = bf2f(gate_in[(size_t)row * 2048 + col]);
          ((u16*)outp)[(size_t)row * 4096 + 2048 + col] = f2bf(g * nv);
        } else if (EPI == 3) {
          pp[(size_t)row * ldo + col] = v;
        }
      }
    }
  }
}

// ---------------- split-K reduce: out = p0+p1+p2+p3 (fp32) ----------------
__global__ void reduce4(const float* __restrict__ p0, const float* __restrict__ p1,
                        const float* __restrict__ p2, const float* __restrict__ p3,
                        float* __restrict__ out) {
  const int n4 = MROWS * DMODEL / 4;
  for (int i = blockIdx.x * 256 + threadIdx.x; i < n4; i += gridDim.x * 256) {
    float4 a = ((const float4*)p0)[i];
    float4 b = ((const float4*)p1)[i];
    float4 c = ((const float4*)p2)[i];
    float4 d = ((const float4*)p3)[i];
    float4 o;
    o.x = (a.x + b.x) + (c.x + d.x);
    o.y = (a.y + b.y) + (c.y + d.y);
    o.z = (a.z + b.z) + (c.z + d.z);
    o.w = (a.w + b.w) + (c.w + d.w);
    ((float4*)out)[i] = o;
  }
}

// ---------------- fused prep: conv1d+SiLU+split | mlp_skip | dt ----------------
#define NB_CONV 33280   // MROWS*DXBC/256
#define NB_MLP  8192    // MROWS*512/256
#define NB_DT   128     // MROWS*8/256

__global__ void prep_kernel(const u16* __restrict__ zx, const float* __restrict__ cw,
                            const float* __restrict__ cb, u16* __restrict__ xc,
                            float* __restrict__ bc, u16* __restrict__ hcat,
                            const float* __restrict__ dt_bias, float* __restrict__ dtb) {
  int blk = blockIdx.x;
  if (blk < NB_CONV) {
    int idx = blk * 256 + threadIdx.x;
    if (idx >= MROWS * DXBC) return;
    int c = idx % DXBC;
    int m = idx / DXBC;
    int l = m & (SEQLEN - 1);
    float acc = cb[c];
    float w0 = cw[c * 4 + 0], w1 = cw[c * 4 + 1], w2 = cw[c * 4 + 2], w3 = cw[c * 4 + 3];
    const u16* col = zx + (size_t)m * NPAD + 4096 + c;
    acc += w3 * bf2f(col[0]);
    if (l >= 1) acc += w2 * bf2f(col[-NPAD]);
    if (l >= 2) acc += w1 * bf2f(col[-2 * NPAD]);
    if (l >= 3) acc += w0 * bf2f(col[-3 * NPAD]);
    float sv = acc / (1.f + __expf(-acc));
    if (c < DINNER) xc[(size_t)m * DINNER + c] = f2bf(sv);
    else bc[(size_t)m * 32 + (c - DINNER)] = sv;
  } else if (blk < NB_CONV + NB_MLP) {
    int i = (blk - NB_CONV) * 256 + threadIdx.x;
    int m = i >> 9, c4 = (i & 511) * 4;
    const u16* row = zx + (size_t)m * NPAD;
    ushort4 zv = *(const ushort4*)(row + c4);
    ushort4 xv = *(const ushort4*)(row + 2048 + c4);
    float z0, x0;
    ushort4 o;
    z0 = bf2f(zv.x); x0 = bf2f(xv.x); o.x = f2bf(x0 * z0 / (1.f + __expf(-z0)));
    z0 = bf2f(zv.y); x0 = bf2f(xv.y); o.y = f2bf(x0 * z0 / (1.f + __expf(-z0)));
    z0 = bf2f(zv.z); x0 = bf2f(xv.z); o.z = f2bf(x0 * z0 / (1.f + __expf(-z0)));
    z0 = bf2f(zv.w); x0 = bf2f(xv.w); o.w = f2bf(x0 * z0 / (1.f + __expf(-z0)));
    *(ushort4*)(hcat + (size_t)m * 4096 + c4) = o;
  } else {
    int idx = (blk - NB_CONV - NB_MLP) * 256 + threadIdx.x;
    if (idx >= MROWS * NHEADS) return;
    int hd = idx & 7, m = idx >> 3;
    float raw = bf2f(zx[(size_t)m * NPAD + 6176 + hd]) + dt_bias[hd];
    float dtv = raw > 20.f ? raw : log1pf(expf(raw));
    dtb[idx] = dtv;
  }
}

// ================= SSD chunked scan =================
__device__ __forceinline__ int xs_addr(int r, int p) {  // byte offset
  return r * 512 + ((((p >> 3) ^ ((r >> 3) & 3)) & 31) << 4) + (p & 7) * 2;
}
__device__ __forceinline__ int P_addr(int t, int s) {   // byte offset, 64x64 bf16
  return t * 128 + ((((s >> 3) ^ (t & 7)) & 7) << 4) + (s & 7) * 2;
}

__device__ __forceinline__ void stage_x(u16* xs, const u16* __restrict__ xc,
                                        size_t base, int tid) {
  #pragma unroll
  for (int it = 0; it < 8; ++it) {
    int r = it * 8 + (tid >> 5);
    int pc = (tid & 31) * 8;
    short8 v = *(const short8*)(xc + base + (size_t)r * DINNER + pc);
    *(short8*)((char*)xs + xs_addr(r, pc)) = v;
  }
}

__device__ __forceinline__ short8 xfrag(const u16* xs, int k0, int g, int p) {
  short8 v;
  #pragma unroll
  for (int j = 0; j < 8; ++j) {
    int s = k0 + g * 8 + j;
    v[j] = *(const short*)((const char*)xs + xs_addr(s, p));
  }
  return v;
}

// S1: per-(bh,chunk) state S_c[n][p] and log-decay prefix lc
__global__ __launch_bounds__(256) void ssd_state(
    const u16* __restrict__ xc, const float* __restrict__ bcb,
    const float* __restrict__ dtb, const float* __restrict__ A_log,
    float* __restrict__ Sbuf, float* __restrict__ lcbuf) {
  __shared__ u16 xs[64 * 256];
  __shared__ float sLC[64], sDT[64];
  __shared__ float wBT[16][65];
  const int tid = threadIdx.x;
  const int bh = blockIdx.x >> 5, c = blockIdx.x & 31;
  const int b = bh >> 3, h = bh & 7;
  const size_t row0 = (size_t)b * SEQLEN + c * CHUNK;
  stage_x(xs, xc, row0 * DINNER + h * HEADDIM, tid);
  if (tid < 64) {
    float dtv = dtb[(row0 + tid) * NHEADS + h];
    float A = -__expf(A_log[h]);
    float s = dtv * A;
    #pragma unroll
    for (int off = 1; off < 64; off <<= 1) {
      float v = __shfl_up(s, off, 64);
      if (tid >= off) s += v;
    }
    sLC[tid] = s; sDT[tid] = dtv;
    lcbuf[(size_t)blockIdx.x * 64 + tid] = s;
  }
  __syncthreads();
  const float lc63 = sLC[63];
  for (int i = tid; i < 1024; i += 256) {
    int n = i & 15, t = i >> 4;
    float w = sDT[t] * __expf(lc63 - sLC[t]);
    wBT[n][t] = w * bcb[(row0 + t) * 32 + n];
  }
  __syncthreads();
  const int lane = tid & 63, w = tid >> 6;
  const int cl = lane & 15, g = lane >> 4;
  f32x4 acc[4];
  #pragma unroll
  for (int pt = 0; pt < 4; ++pt) acc[pt] = (f32x4){0.f, 0.f, 0.f, 0.f};
  #pragma unroll
  for (int kk = 0; kk < 2; ++kk) {
    int k0 = kk * 32;
    short8 af;
    #pragma unroll
    for (int j = 0; j < 8; ++j) af[j] = (short)f2bf(wBT[cl][k0 + g * 8 + j]);
    #pragma unroll
    for (int pt = 0; pt < 4; ++pt) {
      short8 bf = xfrag(xs, k0, g, (w * 4 + pt) * 16 + cl);
      acc[pt] = __builtin_amdgcn_mfma_f32_16x16x32_bf16(af, bf, acc[pt], 0, 0, 0);
    }
  }
  float* Sc = Sbuf + (size_t)blockIdx.x * 16 * 256;
  #pragma unroll
  for (int pt = 0; pt < 4; ++pt)
    #pragma unroll
    for (int j = 0; j < 4; ++j)
      Sc[(g * 4 + j) * 256 + (w * 4 + pt) * 16 + cl] = acc[pt][j];
}

// S2: inter-chunk recurrence Sprev[c] = H_{c-1}
__global__ __launch_bounds__(256) void ssd_combine(
    const float* __restrict__ Sbuf, const float* __restrict__ lcbuf,
    float* __restrict__ Sprev) {
  const int bh = blockIdx.x >> 4, seg = blockIdx.x & 15;
  const int idx = seg * 256 + threadIdx.x;   // n*256+p
  float r = 0.f;
  #pragma unroll 1
  for (int c = 0; c < NCHUNK; ++c) {
    size_t o = ((size_t)bh * NCHUNK + c) * 4096 + idx;
    Sprev[o] = r;
    float lam = __expf(lcbuf[((size_t)bh * NCHUNK + c) * 64 + 63]);
    r = lam * r + Sbuf[o];
  }
}

// S3: intra-chunk (CB^T masked) @ X + Ce @ Sprev^T + D*x -> y (bf16)
__global__ __launch_bounds__(256) void ssd_out(
    const u16* __restrict__ xc, const float* __restrict__ bcb,
    const float* __restrict__ dtb, const float* __restrict__ lcbuf,
    const float* __restrict__ Sprev, const float* __restrict__ D_par,
    u16* __restrict__ y) {
  __shared__ u16 xs[64 * 256];
  __shared__ u16 P[64 * 64];
  __shared__ u16 sB[64][17], sC[64][17], sCe[64][17];
  __shared__ u16 sSp[256][17];
  __shared__ float sLC[64], sDT[64];
  const int tid = threadIdx.x;
  const int bh = blockIdx.x >> 5, c = blockIdx.x & 31;
  const int b = bh >> 3, h = bh & 7;
  const size_t row0 = (size_t)b * SEQLEN + c * CHUNK;
  stage_x(xs, xc, row0 * DINNER + h * HEADDIM, tid);
  if (tid < 64) {
    sLC[tid] = lcbuf[(size_t)blockIdx.x * 64 + tid];
    sDT[tid] = dtb[(row0 + tid) * NHEADS + h];
  }
  for (int i = tid; i < 1024; i += 256) {
    int n = i & 15, t = i >> 4;
    float Bv = bcb[(row0 + t) * 32 + n];
    float Cv = bcb[(row0 + t) * 32 + 16 + n];
    float e = __expf(lcbuf[(size_t)blockIdx.x * 64 + t]);
    sB[t][n] = f2bf(Bv);
    sC[t][n] = f2bf(Cv);
    sCe[t][n] = f2bf(Cv * e);
  }
  {
    const float* Sp = Sprev + (size_t)blockIdx.x * 4096;
    int p = tid & 255;
    if (tid < 256) {
      #pragma unroll
      for (int n = 0; n < 16; ++n) sSp[p][n] = f2bf(Sp[n * 256 + p]);
    }
  }
  __syncthreads();

  const int lane = tid & 63, w = tid >> 6;
  const int cl = lane & 15, g = lane >> 4;

  // ---- CB^T (K=16, zero-padded to 32) ----
  f32x4 gacc[4];
  #pragma unroll
  for (int st = 0; st < 4; ++st) gacc[st] = (f32x4){0.f, 0.f, 0.f, 0.f};
  short8 afc = (short8){0, 0, 0, 0, 0, 0, 0, 0};
  if (g < 2) {
    #pragma unroll
    for (int j = 0; j < 8; ++j) afc[j] = (short)sC[w * 16 + cl][g * 8 + j];
  }
  #pragma unroll
  for (int st = 0; st < 4; ++st) {
    short8 bfb = (short8){0, 0, 0, 0, 0, 0, 0, 0};
    if (g < 2) {
      #pragma unroll
      for (int j = 0; j < 8; ++j) bfb[j] = (short)sB[st * 16 + cl][g * 8 + j];
    }
    gacc[st] = __builtin_amdgcn_mfma_f32_16x16x32_bf16(afc, bfb, gacc[st], 0, 0, 0);
  }
  // ---- scale/mask -> P ----
  #pragma unroll
  for (int st = 0; st < 4; ++st) {
    #pragma unroll
    for (int j = 0; j < 4; ++j) {
      int t = w * 16 + g * 4 + j;
      int s = st * 16 + cl;
      float v = 0.f;
      if (s <= t) v = gacc[st][j] * sDT[s] * __expf(sLC[t] - sLC[s]);
      *(u16*)((char*)P + P_addr(t, s)) = f2bf(v);
    }
  }
  asm volatile("s_waitcnt lgkmcnt(0)" ::: "memory");
  __builtin_amdgcn_sched_barrier(0);

  // ---- Y = P@X (K=64) + Ce@Sp^T (K=16) ----
  f32x4 acc[16];
  #pragma unroll
  for (int pt = 0; pt < 16; ++pt) acc[pt] = (f32x4){0.f, 0.f, 0.f, 0.f};
  #pragma unroll
  for (int kk = 0; kk < 2; ++kk) {
    int k0 = kk * 32;
    short8 ap = *(const short8*)((const char*)P + P_addr(w * 16 + cl, k0 + g * 8));
    #pragma unroll
    for (int pt = 0; pt < 16; ++pt) {
      short8 bf = xfrag(xs, k0, g, pt * 16 + cl);
      acc[pt] = __builtin_amdgcn_mfma_f32_16x16x32_bf16(ap, bf, acc[pt], 0, 0, 0);
    }
  }
  {
    short8 ae = (short8){0, 0, 0, 0, 0, 0, 0, 0};
    if (g < 2) {
      #pragma unroll
      for (int j = 0; j < 8; ++j) ae[j] = (short)sCe[w * 16 + cl][g * 8 + j];
    }
    #pragma unroll
    for (int pt = 0; pt < 16; ++pt) {
      short8 bs = (short8){0, 0, 0, 0, 0, 0, 0, 0};
      if (g < 2) {
        #pragma unroll
        for (int j = 0; j < 8; ++j) bs[j] = (short)sSp[pt * 16 + cl][g * 8 + j];
      }
      acc[pt] = __builtin_amdgcn_mfma_f32_16x16x32_bf16(ae, bs, acc[pt], 0, 0, 0);
    }
  }
  const float Dv = D_par[h];
  #pragma unroll
  for (int pt = 0; pt < 16; ++pt) {
    #pragma unroll
    for (int j = 0; j < 4; ++j) {
      int t = w * 16 + g * 4 + j;
      int p = pt * 16 + cl;
      float xv = bf2f(*(const u16*)((const char*)xs + xs_addr(t, p)));
      float v = acc[pt][j] + Dv * xv;
      y[(row0 + t) * DINNER + h * HEADDIM + p] = f2bf(v);
    }
  }
}

// ---------------- layernorm (bf16 in) -> bf16 ----------------
__global__ __launch_bounds__(256) void ln_kernel(const u16* __restrict__ y,
                                                 const float* __restrict__ gamma,
                                                 const float* __restrict__ beta,
                                                 u16* __restrict__ nrm) {
  const int row = blockIdx.x;
  const int t = threadIdx.x;
  const u16* yr = y + (size_t)row * DINNER;
  short8 v = *(const short8*)(yr + t * 8);
  float f[8];
  float s = 0.f, ss = 0.f;
  #pragma unroll
  for (int j = 0; j < 8; ++j) {
    f[j] = bf2f((u16)v[j]);
    s += f[j]; ss += f[j] * f[j];
  }
  #pragma unroll
  for (int o = 1; o < 64; o <<= 1) { s += __shfl_xor(s, o); ss += __shfl_xor(ss, o); }
  __shared__ float rs[4], rss[4];
  const int wid = t >> 6;
  if ((t & 63) == 0) { rs[wid] = s; rss[wid] = ss; }
  __syncthreads();
  s = rs[0] + rs[1] + rs[2] + rs[3];
  ss = rss[0] + rss[1] + rss[2] + rss[3];
  float mu = s * (1.f / DINNER);
  float var = ss * (1.f / DINNER) - mu * mu;
  float inv = rsqrtf(var + 1e-5f);
  float4 g0 = ((const float4*)gamma)[t * 2], g1 = ((const float4*)gamma)[t * 2 + 1];
  float4 b0 = ((const float4*)beta)[t * 2], b1 = ((const float4*)beta)[t * 2 + 1];
  short8 o;
  o[0] = (short)f2bf((f[0] - mu) * inv * g0.x + b0.x);
  o[1] = (short)f2bf((f[1] - mu) * inv * g0.y + b0.y);
  o[2] = (short)f2bf((f[2] - mu) * inv * g0.z + b0.z);
  o[3] = (short)f2bf((f[3] - mu) * inv * g0.w + b0.w);
  o[4] = (short)f2bf((f[4] - mu) * inv * g1.x + b1.x);
  o[5] = (short)f2bf((f[5] - mu) * inv * g1.y + b1.y);
  o[6] = (short)f2bf((f[6] - mu) * inv * g1.z + b1.z);
  o[7] = (short)f2bf((f[7] - mu) * inv * g1.w + b1.w);
  *(short8*)(nrm + (size_t)row * DINNER + t * 8) = o;
}

// ---------------- host ----------------
extern "C" void kernel_launch(void* const* d_in, const int* in_sizes, int n_in,
                              void* d_out, int out_size, void* d_ws, size_t ws_size,
                              hipStream_t stream) {
  (void)in_sizes; (void)n_in; (void)out_size; (void)ws_size;
  const float* u       = (const float*)d_in[0];
  const float* W_in    = (const float*)d_in[1];
  const float* conv_w  = (const float*)d_in[2];
  const float* conv_b  = (const float*)d_in[3];
  const float* dt_bias = (const float*)d_in[4];
  const float* A_log   = (const float*)d_in[5];
  const float* D_par   = (const float*)d_in[6];
  const float* ln_g    = (const float*)d_in[7];
  const float* ln_b    = (const float*)d_in[8];
  const float* W_gate  = (const float*)d_in[9];
  const float* b_gate  = (const float*)d_in[10];
  const float* W_out   = (const float*)d_in[11];
  float* out = (float*)d_out;

  size_t off = 0;
  auto take = [&](size_t bytes) -> char* {
    char* p = (char*)d_ws + off;
    off = (off + bytes + 255) & ~(size_t)255;
    return p;
  };
  u16* u16b  = (u16*)take((size_t)MROWS * DMODEL * 2);          // dead after gemm0
  u16* Wp    = (u16*)take((size_t)NPAD * DMODEL * 2);           // dead after gemm0
  u16* Wg    = (u16*)take((size_t)DINNER * DINNER * 2);         // dead after gemm1
  u16* Wo    = (u16*)take((size_t)DMODEL * 2 * DINNER * 2);
  u16* zx    = (u16*)take((size_t)MROWS * NPAD * 2);            // 49MiB
  u16* xc    = (u16*)take((size_t)MROWS * DINNER * 2);
  float* bcb = (float*)take((size_t)MROWS * 32 * 4);
  float* dtb = (float*)take((size_t)MROWS * NHEADS * 4);
  float* lcbuf = (float*)take((size_t)BH * NCHUNK * 64 * 4);
  u16* nrm   = (u16*)take((size_t)MROWS * DINNER * 2);          // dead after gemm1
  u16* hcat  = (u16*)take((size_t)MROWS * 2 * DINNER * 2);
  float* Sbuf  = (float*)u16b;                // 8MiB alias (u16b dead)
  u16*   y     = zx;                          // bf16 [4096][2048] = 16MiB
  float* Sprev = (float*)((char*)zx + (size_t)16 * 1024 * 1024); // 8MiB alias

  // split-K partial planes (16MiB each), aliased over dead regions during gemm2:
  Parts parts;
  parts.p0 = (float*)zx;                                         // y dead after ln
  parts.p1 = (float*)((char*)zx + (size_t)16 * 1024 * 1024);     // Sprev dead
  parts.p2 = (float*)nrm;                                        // dead after gemm1
  parts.p3 = (float*)d_ws;                                       // u16b/Wp dead

  cvt_all<<<4096, 256, 0, stream>>>(u, W_gate, W_out, W_in, u16b, Wg, Wo, Wp);

  gemm_nt<0><<<dim3(MROWS / 128, NPAD / 128), 256, 0, stream>>>(
      u16b, Wp, DMODEL, DMODEL, NPAD, zx, nullptr, nullptr, parts);

  prep_kernel<<<NB_CONV + NB_MLP + NB_DT, 256, 0, stream>>>(
      zx, conv_w, conv_b, xc, bcb, hcat, dt_bias, dtb);

  ssd_state<<<BH * NCHUNK, 256, 0, stream>>>(xc, bcb, dtb, A_log, Sbuf, lcbuf);
  ssd_combine<<<BH * 16, 256, 0, stream>>>(Sbuf, lcbuf, Sprev);
  ssd_out<<<BH * NCHUNK, 256, 0, stream>>>(xc, bcb, dtb, lcbuf, Sprev, D_par, y);

  ln_kernel<<<MROWS, 256, 0, stream>>>(y, ln_g, ln_b, nrm);

  gemm_nt<1><<<dim3(MROWS / 128, DINNER / 128), 256, 0, stream>>>(
      nrm, Wg, DINNER, DINNER, DINNER, hcat, b_gate, nrm, parts);

  gemm_nt<3><<<dim3(MROWS / 128, DMODEL / 128, 4), 256, 0, stream>>>(
      hcat, Wo, 2 * DINNER / 4, 2 * DINNER, DMODEL, nullptr, nullptr, nullptr, parts);

  reduce4<<<2048, 256, 0, stream>>>(parts.p0, parts.p1, parts.p2, parts.p3, out);
}